// Round 4
// baseline (146.739 us; speedup 1.0000x reference)
//
#include <hip/hip_runtime.h>
#include <math.h>

#define NN 8192
#define DD 128
#define JR 16                   // j-ranges; each wave covers 512 cols
#define KE 14.42695040888963f   // 10*log2(e): exp(10*d) = exp2(KE*d)
#define NCLS 33

typedef __attribute__((ext_vector_type(8))) short short8;
typedef __attribute__((ext_vector_type(4))) float f32x4;

__device__ __forceinline__ unsigned short f2bf(float f) {
    unsigned u = __builtin_bit_cast(unsigned, f);
    unsigned r = (u + 0x7FFFu + ((u >> 16) & 1u)) >> 16;
    return (unsigned short)r;
}
__device__ __forceinline__ float bf2f(unsigned short h) {
    unsigned u = ((unsigned)h) << 16;
    return __builtin_bit_cast(float, u);
}

// ------- kernel 1: normalize rows -> bf16, selfdot of rounded row -------
__global__ __launch_bounds__(256) void prep_kernel(const float* __restrict__ x,
                                                   unsigned short* __restrict__ xn,
                                                   float* __restrict__ sd) {
    int row  = (blockIdx.x << 2) + (threadIdx.x >> 6);
    int lane = threadIdx.x & 63;
    float2 v = ((const float2*)(x + (size_t)row * DD))[lane];
    float ss = v.x * v.x + v.y * v.y;
    #pragma unroll
    for (int off = 32; off; off >>= 1) ss += __shfl_xor(ss, off);
    float rn = rsqrtf(ss);
    unsigned short bx = f2bf(v.x * rn), by = f2bf(v.y * rn);
    ushort2 st; st.x = bx; st.y = by;
    ((ushort2*)(xn + (size_t)row * DD))[lane] = st;
    float fx = bf2f(bx), fy = bf2f(by);
    float s2 = fx * fx + fy * fy;
    #pragma unroll
    for (int off = 32; off; off >>= 1) s2 += __shfl_xor(s2, off);
    if (lane == 0) sd[row] = s2;
}

// ------- kernel 2: per-class feature sums (partials) + label histogram -------
// 64 blocks x 256 thr; block handles 128 rows. LDS-local accumulation.
__global__ __launch_bounds__(256) void gsum_kernel(const unsigned short* __restrict__ xn,
                                                   const int* __restrict__ labels,
                                                   float* __restrict__ Gpart,
                                                   int* __restrict__ cntpart) {
    __shared__ float Gl[2][NCLS][DD];   // 33792 B
    __shared__ int   ch[NCLS];
    const int t = threadIdx.x;
    const int rbase = blockIdx.x * 128;
    for (int i = t; i < 2 * NCLS * DD; i += 256) ((float*)Gl)[i] = 0.f;
    if (t < NCLS) ch[t] = 0;
    __syncthreads();
    if (t < 128) atomicAdd(&ch[labels[rbase + t]], 1);
    const int g = t >> 7, f = t & 127;
    #pragma unroll 4
    for (int k = 0; k < 64; ++k) {
        int r = rbase + g * 64 + k;
        int c = labels[r];
        Gl[g][c][f] += bf2f(xn[(size_t)r * DD + f]);
    }
    __syncthreads();
    for (int i = t; i < NCLS * DD; i += 256)
        Gpart[(size_t)blockIdx.x * (NCLS * DD) + i] = ((float*)Gl)[i] + ((float*)Gl)[NCLS * DD + i];
    if (t < NCLS) cntpart[blockIdx.x * NCLS + t] = ch[t];
}

// ------- kernel 3: reduce G partials + counts -------
__global__ __launch_bounds__(128) void greduce_kernel(const float* __restrict__ Gpart,
                                                      const int* __restrict__ cntpart,
                                                      float* __restrict__ G,
                                                      int* __restrict__ cnt) {
    const int c = blockIdx.x, f = threadIdx.x;
    float s = 0.f;
    #pragma unroll 8
    for (int k = 0; k < 64; ++k) s += Gpart[(size_t)k * (NCLS * DD) + c * DD + f];
    G[c * DD + f] = s;
    if (f == 0) {
        int s2 = 0;
        for (int k = 0; k < 64; ++k) s2 += cntpart[k * NCLS + c];
        cnt[c] = s2;
    }
}

// ------- kernel 4: MFMA similarity + exp accumulation (Z only) -------
// Wave owns 32 rows x 512 cols. 1024 blocks = 4/CU; 4 waves/block convoy on
// the same j-range (L1 B-tile sharing via per-tile barrier). No labels here.
__global__ __launch_bounds__(256, 4) void cl_main(const unsigned short* __restrict__ xn,
                                                  float* __restrict__ Zp) {
    const int tid  = threadIdx.x;
    const int wi   = tid >> 6;
    const int lane = tid & 63;
    const int l15  = lane & 15;
    const int lhi  = lane >> 4;
    const int b    = (int)blockIdx.x;
    const int jr   = b & (JR - 1);
    const int sg   = b >> 4;                 // 0..63
    const int strip = sg * 4 + wi;           // 0..255
    const int row0  = strip * 32;

    // A frags: lane holds A[row0 + mi*16 + l15][ks*32 + lhi*8 .. +7]
    short8 a[2][4];
    #pragma unroll
    for (int mi = 0; mi < 2; ++mi)
        #pragma unroll
        for (int ks = 0; ks < 4; ++ks)
            a[mi][ks] = *(const short8*)(xn + (size_t)(row0 + mi * 16 + l15) * DD + ks * 32 + lhi * 8);

    float z[2][4];
    #pragma unroll
    for (int mi = 0; mi < 2; ++mi)
        #pragma unroll
        for (int r = 0; r < 4; ++r) z[mi][r] = 0.f;

    const int j0r = jr * (NN / JR);
    for (int t8 = 0; t8 < (NN / JR) / 64; ++t8) {   // 8 j-tiles of 64 cols
        __syncthreads();                            // convoy the 4 waves -> L1 reuse
        const int j0 = j0r + t8 * 64;

        f32x4 acc[2][4];
        #pragma unroll
        for (int mi = 0; mi < 2; ++mi)
            #pragma unroll
            for (int ni = 0; ni < 4; ++ni) acc[mi][ni] = (f32x4){0.f, 0.f, 0.f, 0.f};

        #pragma unroll
        for (int ni = 0; ni < 4; ++ni) {
            short8 bf[4];
            #pragma unroll
            for (int ks = 0; ks < 4; ++ks)
                bf[ks] = *(const short8*)(xn + (size_t)(j0 + ni * 16 + l15) * DD + ks * 32 + lhi * 8);
            #pragma unroll
            for (int ks = 0; ks < 4; ++ks)
                #pragma unroll
                for (int mi = 0; mi < 2; ++mi)
                    acc[mi][ni] = __builtin_amdgcn_mfma_f32_16x16x32_bf16(a[mi][ks], bf[ks], acc[mi][ni], 0, 0, 0);
        }

        #pragma unroll
        for (int mi = 0; mi < 2; ++mi)
            #pragma unroll
            for (int ni = 0; ni < 4; ++ni)
                #pragma unroll
                for (int r = 0; r < 4; ++r)
                    z[mi][r] += __builtin_amdgcn_exp2f(acc[mi][ni][r] * KE);
    }

    // reduce across the 16 lanes (columns) sharing each row; write Z partials
    #pragma unroll
    for (int mi = 0; mi < 2; ++mi)
        #pragma unroll
        for (int r = 0; r < 4; ++r) {
            float zz = z[mi][r];
            #pragma unroll
            for (int off = 1; off < 16; off <<= 1) zz += __shfl_xor(zz, off);
            if (l15 == 0)
                Zp[(size_t)jr * NN + row0 + mi * 16 + lhi * 4 + r] = zz;
        }
}

// ------- kernel 5: per-row finalize (Z sum, S via class-sums) -------
__global__ __launch_bounds__(256) void fin1(const float* __restrict__ Zp,
                                            const unsigned short* __restrict__ xn,
                                            const float* __restrict__ G,
                                            const int* __restrict__ cnt,
                                            const float* __restrict__ sd,
                                            const int* __restrict__ labels,
                                            float* __restrict__ psum,
                                            float* __restrict__ pcnt) {
    __shared__ float rs[4], rc[4];
    const int t = threadIdx.x;
    const int row = blockIdx.x * 256 + t;

    float Z = 0.f;
    #pragma unroll
    for (int jr = 0; jr < JR; ++jr) Z += Zp[(size_t)jr * NN + row];
    float sv = sd[row];
    Z -= __builtin_amdgcn_exp2f(sv * KE);          // remove self from denominator

    const int c = labels[row];
    const float* gc = G + c * DD;
    float S = 0.f;
    #pragma unroll 4
    for (int k = 0; k < DD / 8; ++k) {
        short8 v = *(const short8*)(xn + (size_t)row * DD + k * 8);
        #pragma unroll
        for (int e = 0; e < 8; ++e)
            S = fmaf(bf2f((unsigned short)v[e]), gc[k * 8 + e], S);
    }
    S -= sv;                                       // remove self from positive-sum

    int C = cnt[c] - 1;
    float pr = 0.f, vl = 0.f;
    if (C > 0) { pr = 10.f * S / (float)C - logf(Z); vl = 1.f; }
    #pragma unroll
    for (int off = 32; off; off >>= 1) { pr += __shfl_xor(pr, off); vl += __shfl_xor(vl, off); }
    int wv = t >> 6, ln = t & 63;
    if (ln == 0) { rs[wv] = pr; rc[wv] = vl; }
    __syncthreads();
    if (t == 0) {
        psum[blockIdx.x] = rs[0] + rs[1] + rs[2] + rs[3];
        pcnt[blockIdx.x] = rc[0] + rc[1] + rc[2] + rc[3];
    }
}

__global__ void fin2(const float* __restrict__ psum, const float* __restrict__ pcnt,
                     float* __restrict__ out) {
    int t = threadIdx.x;
    float a = t < 32 ? psum[t] : 0.f;
    float c = t < 32 ? pcnt[t] : 0.f;
    #pragma unroll
    for (int off = 32; off; off >>= 1) { a += __shfl_xor(a, off); c += __shfl_xor(c, off); }
    if (t == 0) out[0] = -a / c;
}

extern "C" void kernel_launch(void* const* d_in, const int* in_sizes, int n_in,
                              void* d_out, int out_size, void* d_ws, size_t ws_size,
                              hipStream_t stream) {
    const float* x      = (const float*)d_in[0];
    const int*   labels = (const int*)d_in[1];
    float* out = (float*)d_out;
    char*  ws  = (char*)d_ws;

    size_t off = 0;
    unsigned short* xn = (unsigned short*)(ws + off); off += (size_t)NN * DD * 2;        // 2 MB
    float* sd      = (float*)(ws + off); off += (size_t)NN * 4;                          // 32 KB
    float* Zp      = (float*)(ws + off); off += (size_t)JR * NN * 4;                     // 512 KB
    float* Gpart   = (float*)(ws + off); off += (size_t)64 * NCLS * DD * 4;              // 1.06 MB
    int*   cntpart = (int*)(ws + off);   off += (size_t)64 * NCLS * 4;                   // 8.4 KB
    float* G       = (float*)(ws + off); off += (size_t)NCLS * DD * 4;                   // 16.9 KB
    int*   cnt     = (int*)(ws + off);   off += 256;
    float* psum    = (float*)(ws + off); off += 128;
    float* pcnt    = (float*)(ws + off); off += 128;

    prep_kernel<<<NN / 4, 256, 0, stream>>>(x, xn, sd);
    gsum_kernel<<<64, 256, 0, stream>>>(xn, labels, Gpart, cntpart);
    greduce_kernel<<<NCLS, 128, 0, stream>>>(Gpart, cntpart, G, cnt);
    cl_main<<<64 * JR, 256, 0, stream>>>(xn, Zp);
    fin1<<<NN / 256, 256, 0, stream>>>(Zp, xn, G, cnt, sd, labels, psum, pcnt);
    fin2<<<1, 64, 0, stream>>>(psum, pcnt, out);
}

// Round 5
// 105.365 us; speedup vs baseline: 1.3927x; 1.3927x over previous
//
#include <hip/hip_runtime.h>
#include <math.h>

#define NN 8192
#define DD 128
#define JR 16                    // j-ranges; each wave covers 512 cols
#define KE 14.42695040888963f    // 10*log2(e)
#define SQKE 3.7982825f          // sqrt(KE); xn pre-scaled so MFMA emits exp2-ready logits
#define LN2 0.6931471805599453f  // 10/KE
#define NCLS 33

typedef __attribute__((ext_vector_type(8))) short short8;
typedef __attribute__((ext_vector_type(4))) float f32x4;

__device__ __forceinline__ unsigned short f2bf(float f) {
    unsigned u = __builtin_bit_cast(unsigned, f);
    unsigned r = (u + 0x7FFFu + ((u >> 16) & 1u)) >> 16;
    return (unsigned short)r;
}
__device__ __forceinline__ float bf2f(unsigned short h) {
    unsigned u = ((unsigned)h) << 16;
    return __builtin_bit_cast(float, u);
}

// ---- kernel 1: normalize rows, scale by sqrt(KE), cast bf16, selfdot ----
__global__ __launch_bounds__(256) void prep_kernel(const float* __restrict__ x,
                                                   unsigned short* __restrict__ xn,
                                                   float* __restrict__ sd) {
    int row  = (blockIdx.x << 2) + (threadIdx.x >> 6);
    int lane = threadIdx.x & 63;
    float2 v = ((const float2*)(x + (size_t)row * DD))[lane];
    float ss = v.x * v.x + v.y * v.y;
    #pragma unroll
    for (int off = 32; off; off >>= 1) ss += __shfl_xor(ss, off);
    float rs = rsqrtf(ss) * SQKE;
    unsigned short bx = f2bf(v.x * rs), by = f2bf(v.y * rs);
    ushort2 st; st.x = bx; st.y = by;
    ((ushort2*)(xn + (size_t)row * DD))[lane] = st;
    // selfdot of rounded scaled row (= KE * raw selfdot) to cancel diagonal
    float fx = bf2f(bx), fy = bf2f(by);
    float s2 = fx * fx + fy * fy;
    #pragma unroll
    for (int off = 32; off; off >>= 1) s2 += __shfl_xor(s2, off);
    if (lane == 0) sd[row] = s2;
}

// ---- kernel 2: MFMA similarity, software-pipelined B prefetch, no LDS ----
// Wave owns 64 rows x 512 cols. acc already holds KE*dot -> exp2 direct.
__global__ __launch_bounds__(256, 2) void cl_main(const unsigned short* __restrict__ xn,
                                                  const int* __restrict__ labels,
                                                  float* __restrict__ Zp,
                                                  float* __restrict__ Sp) {
    const int tid  = threadIdx.x;
    const int wi   = tid >> 6;
    const int lane = tid & 63;
    const int l15  = lane & 15;
    const int lhi  = lane >> 4;
    const int b    = (int)blockIdx.x;
    const int jr   = b & (JR - 1);
    const int strip = ((b >> 4) << 2) | wi;   // 0..127
    const int row0  = strip << 6;

    // A frags: lane holds A[row0 + mi*16 + l15][ks*32 + lhi*8 .. +7]
    short8 a[4][4];
    #pragma unroll
    for (int mi = 0; mi < 4; ++mi)
        #pragma unroll
        for (int ks = 0; ks < 4; ++ks)
            a[mi][ks] = *(const short8*)(xn + (size_t)(row0 + mi * 16 + l15) * DD + ks * 32 + lhi * 8);

    int labI[4][4];
    #pragma unroll
    for (int mi = 0; mi < 4; ++mi)
        #pragma unroll
        for (int r = 0; r < 4; ++r)
            labI[mi][r] = labels[row0 + mi * 16 + lhi * 4 + r];

    float z[4][4], s[4][4];
    #pragma unroll
    for (int mi = 0; mi < 4; ++mi)
        #pragma unroll
        for (int r = 0; r < 4; ++r) { z[mi][r] = 0.f; s[mi][r] = 0.f; }

    const int j0r = jr * (NN / JR);
    // per-lane base pointers for B groups (group g = 16 cols starting j0r+g*16)
    const unsigned short* jb = xn + (size_t)(j0r + l15) * DD + lhi * 8;
    const int* lb = labels + j0r + l15;

#define LDB(dst, g) do { \
        const unsigned short* _p = jb + (size_t)(g) * (16 * DD); \
        dst[0] = *(const short8*)(_p); \
        dst[1] = *(const short8*)(_p + 32); \
        dst[2] = *(const short8*)(_p + 64); \
        dst[3] = *(const short8*)(_p + 96); \
    } while (0)

#define MM(accni, bf) do { \
        _Pragma("unroll") \
        for (int ks = 0; ks < 4; ++ks) { \
            _Pragma("unroll") \
            for (int mi = 0; mi < 4; ++mi) \
                acc[mi][accni] = __builtin_amdgcn_mfma_f32_16x16x32_bf16(a[mi][ks], bf[ks], acc[mi][accni], 0, 0, 0); \
        } \
    } while (0)

    short8 bf0[4], bf1[4];
    LDB(bf0, 0);
    int lj0 = lb[0];

    for (int t8 = 0; t8 < 8; ++t8) {
        const int g0 = t8 * 4;
        f32x4 acc[4][4];
        #pragma unroll
        for (int mi = 0; mi < 4; ++mi)
            #pragma unroll
            for (int ni = 0; ni < 4; ++ni) acc[mi][ni] = (f32x4){0.f, 0.f, 0.f, 0.f};

        // gi=0: compute bf0(g0), prefetch g0+1 -> bf1
        LDB(bf1, g0 + 1);
        int lj1 = lb[(g0 + 1) * 16];
        MM(0, bf0);
        // gi=1: compute bf1(g0+1), prefetch g0+2 -> bf0
        LDB(bf0, g0 + 2);
        int lj2 = lb[(g0 + 2) * 16];
        MM(1, bf1);
        // gi=2: compute bf0(g0+2), prefetch g0+3 -> bf1
        LDB(bf1, g0 + 3);
        int lj3 = lb[(g0 + 3) * 16];
        MM(2, bf0);
        // gi=3: compute bf1(g0+3), prefetch next tile's group -> bf0
        int lj0n = 0;
        if (t8 < 7) {
            LDB(bf0, g0 + 4);
            lj0n = lb[(g0 + 4) * 16];
        }
        MM(3, bf1);

        // epilogue (overlaps next tile's in-flight loads)
        int ljv[4] = {lj0, lj1, lj2, lj3};
        #pragma unroll
        for (int mi = 0; mi < 4; ++mi)
            #pragma unroll
            for (int ni = 0; ni < 4; ++ni)
                #pragma unroll
                for (int r = 0; r < 4; ++r) {
                    float d = acc[mi][ni][r];
                    z[mi][r] += __builtin_amdgcn_exp2f(d);
                    s[mi][r] += (ljv[ni] == labI[mi][r]) ? d : 0.f;
                }
        lj0 = lj0n;
    }
#undef LDB
#undef MM

    // reduce across the 16 lanes (columns) sharing each row; write partials
    #pragma unroll
    for (int mi = 0; mi < 4; ++mi)
        #pragma unroll
        for (int r = 0; r < 4; ++r) {
            float zz = z[mi][r], ss = s[mi][r];
            #pragma unroll
            for (int off = 1; off < 16; off <<= 1) {
                zz += __shfl_xor(zz, off);
                ss += __shfl_xor(ss, off);
            }
            if (l15 == 0) {
                int row = row0 + mi * 16 + lhi * 4 + r;
                Zp[(size_t)jr * NN + row] = zz;
                Sp[(size_t)jr * NN + row] = ss;
            }
        }
}

// ---- kernel 3: per-row finalize + per-block partial loss ----
__global__ __launch_bounds__(256) void fin1(const float* __restrict__ Zp,
                                            const float* __restrict__ Sp,
                                            const float* __restrict__ sd,
                                            const int* __restrict__ labels,
                                            float* __restrict__ psum,
                                            float* __restrict__ pcnt) {
    __shared__ int cnt[NCLS];
    __shared__ float rs[4], rc[4];
    const int t = threadIdx.x;
    if (t < NCLS) cnt[t] = 0;
    __syncthreads();
    for (int i = t; i < NN; i += 256) atomicAdd(&cnt[labels[i]], 1);
    __syncthreads();

    const int row = blockIdx.x * 256 + t;
    float Z = 0.f, S = 0.f;
    #pragma unroll
    for (int jr = 0; jr < JR; ++jr) {
        Z += Zp[(size_t)jr * NN + row];
        S += Sp[(size_t)jr * NN + row];
    }
    float sv = sd[row];
    Z -= __builtin_amdgcn_exp2f(sv);   // remove self from denominator
    S -= sv;                           // remove self from positive-sum (scaled units)
    int C = cnt[labels[row]] - 1;
    float pr = 0.f, vl = 0.f;
    if (C > 0) { pr = LN2 * S / (float)C - logf(Z); vl = 1.f; }
    #pragma unroll
    for (int off = 32; off; off >>= 1) { pr += __shfl_xor(pr, off); vl += __shfl_xor(vl, off); }
    int wv = t >> 6, ln = t & 63;
    if (ln == 0) { rs[wv] = pr; rc[wv] = vl; }
    __syncthreads();
    if (t == 0) {
        psum[blockIdx.x] = rs[0] + rs[1] + rs[2] + rs[3];
        pcnt[blockIdx.x] = rc[0] + rc[1] + rc[2] + rc[3];
    }
}

__global__ void fin2(const float* __restrict__ psum, const float* __restrict__ pcnt,
                     float* __restrict__ out) {
    int t = threadIdx.x;
    float a = t < 32 ? psum[t] : 0.f;
    float c = t < 32 ? pcnt[t] : 0.f;
    #pragma unroll
    for (int off = 32; off; off >>= 1) { a += __shfl_xor(a, off); c += __shfl_xor(c, off); }
    if (t == 0) out[0] = -a / c;
}

extern "C" void kernel_launch(void* const* d_in, const int* in_sizes, int n_in,
                              void* d_out, int out_size, void* d_ws, size_t ws_size,
                              hipStream_t stream) {
    const float* x      = (const float*)d_in[0];
    const int*   labels = (const int*)d_in[1];
    float* out = (float*)d_out;
    char*  ws  = (char*)d_ws;

    size_t off = 0;
    unsigned short* xn = (unsigned short*)(ws + off); off += (size_t)NN * DD * 2;  // 2 MB
    float* sd   = (float*)(ws + off); off += (size_t)NN * 4;                       // 32 KB
    float* Zp   = (float*)(ws + off); off += (size_t)JR * NN * 4;                  // 512 KB
    float* Sp   = (float*)(ws + off); off += (size_t)JR * NN * 4;                  // 512 KB
    float* psum = (float*)(ws + off); off += 128;
    float* pcnt = (float*)(ws + off); off += 128;

    prep_kernel<<<NN / 4, 256, 0, stream>>>(x, xn, sd);
    cl_main<<<(NN / 64 / 4) * JR, 256, 0, stream>>>(xn, labels, Zp, Sp);
    fin1<<<NN / 256, 256, 0, stream>>>(Zp, Sp, sd, labels, psum, pcnt);
    fin2<<<1, 64, 0, stream>>>(psum, pcnt, out);
}

// Round 6
// 91.032 us; speedup vs baseline: 1.6119x; 1.1574x over previous
//
#include <hip/hip_runtime.h>
#include <math.h>

#define NN 8192
#define DD 128
#define JR 16
#define NT ((NN / JR) / 64)      // 8 tiles of 64 cols per block
#define SQKE 3.7982825f          // sqrt(10*log2(e)); xn pre-scaled -> MFMA emits exp2-ready logits
#define LN2 0.6931471805599453f
#define NCLS 33

typedef __attribute__((ext_vector_type(8))) short short8;
typedef __attribute__((ext_vector_type(4))) float f32x4;

__device__ __forceinline__ unsigned short f2bf(float f) {
    unsigned u = __builtin_bit_cast(unsigned, f);
    unsigned r = (u + 0x7FFFu + ((u >> 16) & 1u)) >> 16;
    return (unsigned short)r;
}
__device__ __forceinline__ float bf2f(unsigned short h) {
    unsigned u = ((unsigned)h) << 16;
    return __builtin_bit_cast(float, u);
}

// ---- kernel 1: normalize+scale rows -> bf16, selfdot; zero Z/S/psum/pcnt ----
__global__ __launch_bounds__(256) void prep_kernel(const float* __restrict__ x,
                                                   unsigned short* __restrict__ xn,
                                                   float* __restrict__ sd,
                                                   float* __restrict__ zs) {
    const int b = blockIdx.x, t = threadIdx.x;
    const int zi = b * 256 + t;
    if (zi < 2 * NN + 64) zs[zi] = 0.f;          // Z[NN] S[NN] psum[32] pcnt[32]

    int row  = (b << 2) + (t >> 6);
    int lane = t & 63;
    float2 v = ((const float2*)(x + (size_t)row * DD))[lane];
    float ss = v.x * v.x + v.y * v.y;
    #pragma unroll
    for (int off = 32; off; off >>= 1) ss += __shfl_xor(ss, off);
    float rs = rsqrtf(ss) * SQKE;
    unsigned short bx = f2bf(v.x * rs), by = f2bf(v.y * rs);
    ushort2 st; st.x = bx; st.y = by;
    ((ushort2*)(xn + (size_t)row * DD))[lane] = st;
    float fx = bf2f(bx), fy = bf2f(by);
    float s2 = fx * fx + fy * fy;
    #pragma unroll
    for (int off = 32; off; off >>= 1) s2 += __shfl_xor(s2, off);
    if (lane == 0) sd[row] = s2;
}

// ---- kernel 2: MFMA similarity; LDS-shared B tile, double-buffered ----
// 512 thr = 8 waves; wave owns 64 rows; block covers 512 rows x 512 cols.
__global__ __launch_bounds__(512, 2) void cl_main(const unsigned short* __restrict__ xn,
                                                  const int* __restrict__ labels,
                                                  float* __restrict__ Z,
                                                  float* __restrict__ S) {
    __shared__ __align__(16) unsigned short Bt[2][64][DD];   // 32 KB double buffer

    const int tid  = threadIdx.x;
    const int w    = tid >> 6;
    const int lane = tid & 63;
    const int l15  = lane & 15;
    const int lhi  = lane >> 4;
    const int b    = (int)blockIdx.x;
    const int jr   = b & (JR - 1);
    const int panel = b >> 4;                  // 0..15
    const int row0  = panel * 512 + w * 64;
    const int j0r   = jr * (NN / JR);

    // A frags: lane holds A[row0 + mi*16 + l15][ks*32 + lhi*8 .. +7]
    short8 a[4][4];
    #pragma unroll
    for (int mi = 0; mi < 4; ++mi)
        #pragma unroll
        for (int ks = 0; ks < 4; ++ks)
            a[mi][ks] = *(const short8*)(xn + (size_t)(row0 + mi * 16 + l15) * DD + ks * 32 + lhi * 8);

    int labI[4][4];
    #pragma unroll
    for (int mi = 0; mi < 4; ++mi)
        #pragma unroll
        for (int r = 0; r < 4; ++r)
            labI[mi][r] = labels[row0 + mi * 16 + lhi * 4 + r];

    // staging roles: wave w stages tile rows w*8 .. w*8+7 (two quads of 4 rows)
    // swizzle: LDS slot (row,k) holds global colblk k^(row&7)  (involution)
    const int r4 = lane >> 4, kk = lane & 15;
    const int srow0 = w * 8 + r4;
    const int srow1 = w * 8 + 4 + r4;
    const unsigned short* sg0 = xn + (size_t)(j0r + srow0) * DD + (kk ^ (srow0 & 7)) * 8;
    const unsigned short* sg1 = xn + (size_t)(j0r + srow1) * DD + (kk ^ (srow1 & 7)) * 8;

    float z[4][4], s[4][4];
    #pragma unroll
    for (int mi = 0; mi < 4; ++mi)
        #pragma unroll
        for (int r = 0; r < 4; ++r) { z[mi][r] = 0.f; s[mi][r] = 0.f; }

    // prologue: stage tile 0
    {
        short8 t0 = *(const short8*)sg0;
        short8 t1 = *(const short8*)sg1;
        *(short8*)&Bt[0][srow0][kk * 8] = t0;
        *(short8*)&Bt[0][srow1][kk * 8] = t1;
    }
    __syncthreads();

    const int sw = l15 & 7;
    int cur = 0;
    for (int t8 = 0; t8 < NT; ++t8) {
        const int j0 = j0r + t8 * 64;

        // phase A: issue next tile's global loads (latency hides under compute)
        short8 nx0, nx1;
        if (t8 < NT - 1) {
            nx0 = *(const short8*)(sg0 + (size_t)(t8 + 1) * 64 * DD);
            nx1 = *(const short8*)(sg1 + (size_t)(t8 + 1) * 64 * DD);
        }
        int lj[4];
        #pragma unroll
        for (int ni = 0; ni < 4; ++ni) lj[ni] = labels[j0 + ni * 16 + l15];

        // phase B: compute from Bt[cur]
        const char* rbase = (const char*)&Bt[cur][0][0] + l15 * 256;
        f32x4 acc[4][4];
        #pragma unroll
        for (int mi = 0; mi < 4; ++mi)
            #pragma unroll
            for (int ni = 0; ni < 4; ++ni) acc[mi][ni] = (f32x4){0.f, 0.f, 0.f, 0.f};

        #pragma unroll
        for (int ni = 0; ni < 4; ++ni) {
            short8 bfv[4];
            #pragma unroll
            for (int ks = 0; ks < 4; ++ks)
                bfv[ks] = *(const short8*)(rbase + ni * 4096 + ((((ks << 2) | lhi) ^ sw) << 4));
            #pragma unroll
            for (int ks = 0; ks < 4; ++ks)
                #pragma unroll
                for (int mi = 0; mi < 4; ++mi)
                    acc[mi][ni] = __builtin_amdgcn_mfma_f32_16x16x32_bf16(a[mi][ks], bfv[ks], acc[mi][ni], 0, 0, 0);
        }

        // epilogue: Z += exp2(d); S += d on label match (self removed in fin1)
        #pragma unroll
        for (int mi = 0; mi < 4; ++mi)
            #pragma unroll
            for (int ni = 0; ni < 4; ++ni)
                #pragma unroll
                for (int r = 0; r < 4; ++r) {
                    float d = acc[mi][ni][r];
                    z[mi][r] += __builtin_amdgcn_exp2f(d);
                    s[mi][r] += (lj[ni] == labI[mi][r]) ? d : 0.f;
                }

        // phase C: write staged data into the other buffer
        if (t8 < NT - 1) {
            *(short8*)&Bt[cur ^ 1][srow0][kk * 8] = nx0;
            *(short8*)&Bt[cur ^ 1][srow1][kk * 8] = nx1;
        }
        __syncthreads();
        cur ^= 1;
    }

    // reduce across the 16 col-lanes per row; atomically add into Z/S
    #pragma unroll
    for (int mi = 0; mi < 4; ++mi)
        #pragma unroll
        for (int r = 0; r < 4; ++r) {
            float zz = z[mi][r], ss = s[mi][r];
            #pragma unroll
            for (int off = 1; off < 16; off <<= 1) {
                zz += __shfl_xor(zz, off);
                ss += __shfl_xor(ss, off);
            }
            if (l15 == 0) {
                int row = row0 + mi * 16 + lhi * 4 + r;
                atomicAdd(&Z[row], zz);
                atomicAdd(&S[row], ss);
            }
        }
}

// ---- kernel 3: per-row finalize + per-block partial loss ----
__global__ __launch_bounds__(256) void fin1(const float* __restrict__ Z,
                                            const float* __restrict__ S,
                                            const float* __restrict__ sd,
                                            const int* __restrict__ labels,
                                            float* __restrict__ psum,
                                            float* __restrict__ pcnt) {
    __shared__ int cnt[NCLS];
    __shared__ float rs[4], rc[4];
    const int t = threadIdx.x;
    if (t < NCLS) cnt[t] = 0;
    __syncthreads();
    for (int i = t; i < NN; i += 256) atomicAdd(&cnt[labels[i]], 1);
    __syncthreads();

    const int row = blockIdx.x * 256 + t;
    float Zr = Z[row] - __builtin_amdgcn_exp2f(sd[row]);   // remove self from denominator
    float Sr = S[row] - sd[row];                           // remove self from positive-sum
    int C = cnt[labels[row]] - 1;
    float pr = 0.f, vl = 0.f;
    if (C > 0) { pr = LN2 * Sr / (float)C - logf(Zr); vl = 1.f; }
    #pragma unroll
    for (int off = 32; off; off >>= 1) { pr += __shfl_xor(pr, off); vl += __shfl_xor(vl, off); }
    int wv = t >> 6, ln = t & 63;
    if (ln == 0) { rs[wv] = pr; rc[wv] = vl; }
    __syncthreads();
    if (t == 0) {
        psum[blockIdx.x] = rs[0] + rs[1] + rs[2] + rs[3];
        pcnt[blockIdx.x] = rc[0] + rc[1] + rc[2] + rc[3];
    }
}

__global__ void fin2(const float* __restrict__ psum, const float* __restrict__ pcnt,
                     float* __restrict__ out) {
    int t = threadIdx.x;
    float a = t < 32 ? psum[t] : 0.f;
    float c = t < 32 ? pcnt[t] : 0.f;
    #pragma unroll
    for (int off = 32; off; off >>= 1) { a += __shfl_xor(a, off); c += __shfl_xor(c, off); }
    if (t == 0) out[0] = -a / c;
}

extern "C" void kernel_launch(void* const* d_in, const int* in_sizes, int n_in,
                              void* d_out, int out_size, void* d_ws, size_t ws_size,
                              hipStream_t stream) {
    const float* x      = (const float*)d_in[0];
    const int*   labels = (const int*)d_in[1];
    float* out = (float*)d_out;
    char*  ws  = (char*)d_ws;

    size_t off = 0;
    unsigned short* xn = (unsigned short*)(ws + off); off += (size_t)NN * DD * 2;  // 2 MB
    float* sd = (float*)(ws + off); off += (size_t)NN * 4;                         // 32 KB
    float* zs = (float*)(ws + off); off += (size_t)(2 * NN + 64) * 4;              // 64.25 KB
    float* Z    = zs;
    float* S    = zs + NN;
    float* psum = zs + 2 * NN;
    float* pcnt = zs + 2 * NN + 32;

    prep_kernel<<<NN / 4, 256, 0, stream>>>(x, xn, sd, zs);
    cl_main<<<(NN / 512) * JR, 512, 0, stream>>>(xn, labels, Z, S);
    fin1<<<NN / 256, 256, 0, stream>>>(Z, S, sd, labels, psum, pcnt);
    fin2<<<1, 64, 0, stream>>>(psum, pcnt, out);
}